// Round 1
// baseline (428.677 us; speedup 1.0000x reference)
//
#include <hip/hip_runtime.h>
#include <stdint.h>

#define M_DIM 8192
#define K_DIM 4096
#define N_DIM 4096
#define BM 128
#define BN 128
#define BK 64

typedef __attribute__((ext_vector_type(4))) int i32x4;

// ---------------------------------------------------------------------------
// Pack int32 (values in [-128,127]) -> int8. Each thread packs 16 elements.
// ---------------------------------------------------------------------------
__global__ __launch_bounds__(256) void pack_kernel(const int* __restrict__ src,
                                                   int8_t* __restrict__ dst,
                                                   int n16) {
  int i = blockIdx.x * 256 + threadIdx.x;
  if (i >= n16) return;
  const int4* s = reinterpret_cast<const int4*>(src) + (size_t)i * 4;
  int4 v0 = s[0], v1 = s[1], v2 = s[2], v3 = s[3];
  int4 p;
  p.x = (v0.x & 0xff) | ((v0.y & 0xff) << 8) | ((v0.z & 0xff) << 16) | ((v0.w & 0xff) << 24);
  p.y = (v1.x & 0xff) | ((v1.y & 0xff) << 8) | ((v1.z & 0xff) << 16) | ((v1.w & 0xff) << 24);
  p.z = (v2.x & 0xff) | ((v2.y & 0xff) << 8) | ((v2.z & 0xff) << 16) | ((v2.w & 0xff) << 24);
  p.w = (v3.x & 0xff) | ((v3.y & 0xff) << 8) | ((v3.z & 0xff) << 16) | ((v3.w & 0xff) << 24);
  reinterpret_cast<int4*>(dst)[i] = p;
}

// Writes the second tuple output (out_scale) at out[M*N].
__global__ void tail_kernel(float* __restrict__ out, const float* __restrict__ so) {
  out[(size_t)M_DIM * N_DIM] = so[0];
}

// ---------------------------------------------------------------------------
// m97-structure int8 GEMM: 128x128 tile, BK=64, 4 waves (2x2), each wave owns
// a 64x64 sub-tile = 4x4 fragments of 16x16, mfma_i32_16x16x64_i8.
// A: [M,K] int8 row-major.  B: [N,K] int8 row-major (i.e. B^T, like A).
// DIRECT=true: inputs are the original int32 buffers; pack in-kernel (fallback
// when ws is too small for the packed copies).
// ---------------------------------------------------------------------------
template <bool DIRECT>
__global__ __launch_bounds__(256) void gemm_kernel(
    const int8_t* __restrict__ A8, const int8_t* __restrict__ B8,
    const int* __restrict__ A32, const int* __restrict__ B32,
    float* __restrict__ out,
    const float* __restrict__ sx, const float* __restrict__ sw,
    const float* __restrict__ so) {
  __shared__ int8_t As[BM * BK];  // 8 KiB, row-major [row][k], 64 B/row
  __shared__ int8_t Bs[BN * BK];  // 8 KiB, row-major [col][k]

  const int tid = threadIdx.x;
  const int lane = tid & 63;
  const int wid = tid >> 6;
  const int bid = blockIdx.x;
  const int bm = bid % (M_DIM / BM);  // consecutive bids share the B tile
  const int bn = bid / (M_DIM / BM);
  const size_t arow0 = (size_t)bm * BM;
  const size_t bcol0 = (size_t)bn * BN;

  const int wrr = wid >> 1;   // wave row (0..1) -> 64-row strip
  const int wcc = wid & 1;    // wave col (0..1) -> 64-col strip
  const int lrow = lane & 15; // row (A) / col (B) within 16x16 fragment
  const int kq = lane >> 4;   // k-quarter: 16 bytes at kq*16

  i32x4 acc[4][4] = {};

  for (int kk = 0; kk < K_DIM; kk += BK) {
    if constexpr (!DIRECT) {
#pragma unroll
      for (int i = 0; i < 2; ++i) {
        int loff = i * 4096 + tid * 16;  // lane-linear LDS byte offset
        int r = loff >> 6, c = loff & 63;
        __builtin_amdgcn_global_load_lds(
            (const __attribute__((address_space(1))) void*)(A8 + (arow0 + r) * K_DIM + kk + c),
            (__attribute__((address_space(3))) void*)(As + loff), 16, 0, 0);
        __builtin_amdgcn_global_load_lds(
            (const __attribute__((address_space(1))) void*)(B8 + (bcol0 + r) * K_DIM + kk + c),
            (__attribute__((address_space(3))) void*)(Bs + loff), 16, 0, 0);
      }
    } else {
#pragma unroll
      for (int i = 0; i < 2; ++i) {
        int loff = i * 4096 + tid * 16;
        int r = loff >> 6, c = loff & 63;
        const int4* a4 = reinterpret_cast<const int4*>(A32 + (arow0 + r) * K_DIM + kk + c);
        const int4* b4 = reinterpret_cast<const int4*>(B32 + (bcol0 + r) * K_DIM + kk + c);
        int4 a0 = a4[0], a1 = a4[1], a2 = a4[2], a3 = a4[3];
        int4 b0 = b4[0], b1 = b4[1], b2 = b4[2], b3 = b4[3];
        int4 pa, pb;
        pa.x = (a0.x & 0xff) | ((a0.y & 0xff) << 8) | ((a0.z & 0xff) << 16) | ((a0.w & 0xff) << 24);
        pa.y = (a1.x & 0xff) | ((a1.y & 0xff) << 8) | ((a1.z & 0xff) << 16) | ((a1.w & 0xff) << 24);
        pa.z = (a2.x & 0xff) | ((a2.y & 0xff) << 8) | ((a2.z & 0xff) << 16) | ((a2.w & 0xff) << 24);
        pa.w = (a3.x & 0xff) | ((a3.y & 0xff) << 8) | ((a3.z & 0xff) << 16) | ((a3.w & 0xff) << 24);
        pb.x = (b0.x & 0xff) | ((b0.y & 0xff) << 8) | ((b0.z & 0xff) << 16) | ((b0.w & 0xff) << 24);
        pb.y = (b1.x & 0xff) | ((b1.y & 0xff) << 8) | ((b1.z & 0xff) << 16) | ((b1.w & 0xff) << 24);
        pb.z = (b2.x & 0xff) | ((b2.y & 0xff) << 8) | ((b2.z & 0xff) << 16) | ((b2.w & 0xff) << 24);
        pb.w = (b3.x & 0xff) | ((b3.y & 0xff) << 8) | ((b3.z & 0xff) << 16) | ((b3.w & 0xff) << 24);
        *reinterpret_cast<int4*>(As + loff) = pa;
        *reinterpret_cast<int4*>(Bs + loff) = pb;
      }
    }
    __syncthreads();  // drains vmcnt (global_load_lds) + lgkmcnt

    i32x4 af[4], bf[4];
#pragma unroll
    for (int m = 0; m < 4; ++m)
      af[m] = *reinterpret_cast<const i32x4*>(As + (wrr * 64 + m * 16 + lrow) * BK + kq * 16);
#pragma unroll
    for (int n = 0; n < 4; ++n)
      bf[n] = *reinterpret_cast<const i32x4*>(Bs + (wcc * 64 + n * 16 + lrow) * BK + kq * 16);
#pragma unroll
    for (int m = 0; m < 4; ++m)
#pragma unroll
      for (int n = 0; n < 4; ++n)
        acc[m][n] = __builtin_amdgcn_mfma_i32_16x16x64_i8(af[m], bf[n], acc[m][n], 0, 0, 0);

    __syncthreads();  // protect LDS before next-tile staging
  }

  // Epilogue: dequant -> round-half-even -> clamp -> store as float.
  // C/D layout: col = lane&15, row = (lane>>4)*4 + j (dtype-independent).
  const float scale = sx[0] * sw[0] / so[0];
#pragma unroll
  for (int m = 0; m < 4; ++m) {
#pragma unroll
    for (int n = 0; n < 4; ++n) {
#pragma unroll
      for (int j = 0; j < 4; ++j) {
        int gr = (int)arow0 + wrr * 64 + m * 16 + kq * 4 + j;
        int gc = (int)bcol0 + wcc * 64 + n * 16 + lrow;
        float v = rintf((float)acc[m][n][j] * scale);
        v = fminf(fmaxf(v, -128.f), 127.f);
        out[(size_t)gr * N_DIM + gc] = v;
      }
    }
  }
}

// ---------------------------------------------------------------------------
extern "C" void kernel_launch(void* const* d_in, const int* in_sizes, int n_in,
                              void* d_out, int out_size, void* d_ws, size_t ws_size,
                              hipStream_t stream) {
  const int* x32 = (const int*)d_in[0];
  const float* sx = (const float*)d_in[1];
  const int* w32 = (const int*)d_in[2];
  const float* sw = (const float*)d_in[3];
  const float* so = (const float*)d_in[4];
  float* out = (float*)d_out;

  tail_kernel<<<1, 1, 0, stream>>>(out, so);

  const size_t a_bytes = (size_t)M_DIM * K_DIM;
  const size_t b_bytes = (size_t)N_DIM * K_DIM;
  const int grid = (M_DIM / BM) * (N_DIM / BN);  // 64 * 32 = 2048 blocks

  if (ws_size >= a_bytes + b_bytes) {
    int8_t* A8 = (int8_t*)d_ws;
    int8_t* B8 = A8 + a_bytes;
    pack_kernel<<<(int)(a_bytes / 16 / 256), 256, 0, stream>>>(x32, A8, (int)(a_bytes / 16));
    pack_kernel<<<(int)(b_bytes / 16 / 256), 256, 0, stream>>>(w32, B8, (int)(b_bytes / 16));
    gemm_kernel<false><<<grid, 256, 0, stream>>>(A8, B8, nullptr, nullptr, out, sx, sw, so);
  } else {
    gemm_kernel<true><<<grid, 256, 0, stream>>>(nullptr, nullptr, x32, w32, out, sx, sw, so);
  }
}